// Round 7
// baseline (1008.343 us; speedup 1.0000x reference)
//
#include <hip/hip_runtime.h>
#include <hip/hip_bf16.h>

typedef unsigned short u16;
typedef __attribute__((ext_vector_type(8))) short short8;
typedef __attribute__((ext_vector_type(4))) short s4;
typedef __attribute__((ext_vector_type(4))) float floatx4;

__device__ __forceinline__ float lrelu(float x) { return x > 0.f ? x : 0.01f * x; }

__device__ __forceinline__ short bf16bits(float v) {
  __hip_bfloat16 t = __float2bfloat16(v);
  return *reinterpret_cast<short*>(&t);
}
__device__ __forceinline__ float bits2f(u16 b) {
  __hip_bfloat16 t = *reinterpret_cast<__hip_bfloat16*>(&b);
  return __bfloat162float(t);
}
__device__ __forceinline__ short8 pack8(floatx4 x0, floatx4 x1) {
  short8 b;
#pragma unroll
  for (int r = 0; r < 4; ++r) { b[r] = bf16bits(x0[r]); b[4 + r] = bf16bits(x1[r]); }
  return b;
}

// ---------------------------------------------------------------------------
// Batched transpose+convert: 6 weights W[K][N] f32 -> Wt[N][K] bf16, 1 launch.
// ---------------------------------------------------------------------------
__global__ __launch_bounds__(256) void transpose_all(
    const float* __restrict__ W1, const float* __restrict__ W2,
    const float* __restrict__ W3, const float* __restrict__ W4,
    const float* __restrict__ W5, const float* __restrict__ W6,
    u16* __restrict__ T1, u16* __restrict__ T2, u16* __restrict__ T3,
    u16* __restrict__ T4, u16* __restrict__ T5, u16* __restrict__ T6) {
  const float* W; u16* T; int K, N;
  switch (blockIdx.z) {
    case 0: W = W1; T = T1; K = 128; N = 512; break;
    case 1: W = W2; T = T2; K = 512; N = 512; break;
    case 2: W = W3; T = T3; K = 512; N = 256; break;
    case 3: W = W4; T = T4; K = 256; N = 512; break;
    case 4: W = W5; T = T5; K = 512; N = 512; break;
    default: W = W6; T = T6; K = 512; N = 256; break;
  }
  if ((int)blockIdx.x >= N / 32 || (int)blockIdx.y >= K / 32) return;
  __shared__ u16 tile[32][33];
  const int tx = threadIdx.x & 31;
  const int ty = threadIdx.x >> 5;
  const int n0 = blockIdx.x * 32;
  const int k0 = blockIdx.y * 32;
  for (int i = ty; i < 32; i += 8)
    tile[i][tx] = (u16)bf16bits(W[(size_t)(k0 + i) * N + n0 + tx]);
  __syncthreads();
  for (int i = ty; i < 32; i += 8)
    T[(size_t)(n0 + i) * K + k0 + tx] = tile[tx][i];
}

// ---------------------------------------------------------------------------
// Counting sort of node ids by dag id (2000 bins).
// ---------------------------------------------------------------------------
__global__ __launch_bounds__(256) void hist_kernel(const int* __restrict__ dag,
                                                   int* __restrict__ hist, int n) {
  int i = blockIdx.x * blockDim.x + threadIdx.x;
  if (i < n) atomicAdd(&hist[dag[i]], 1);
}

__global__ __launch_bounds__(256) void scan_offsets(const int* __restrict__ hist,
                                                    int* __restrict__ cursor) {
  __shared__ int part[256];
  const int t = threadIdx.x;
  const int base = t * 8;
  int loc[8];
  int s = 0;
#pragma unroll
  for (int j = 0; j < 8; ++j) {
    int v = (base + j < 2000) ? hist[base + j] : 0;
    loc[j] = s;
    s += v;
  }
  part[t] = s;
  __syncthreads();
  int val = s;
  for (int off = 1; off < 256; off <<= 1) {
    int tmp = (t >= off) ? part[t - off] : 0;
    __syncthreads();
    val += tmp;
    part[t] = val;
    __syncthreads();
  }
  const int chunkBase = (t == 0) ? 0 : part[t - 1];
#pragma unroll
  for (int j = 0; j < 8; ++j)
    if (base + j < 2000) cursor[base + j] = chunkBase + loc[j];
}

__global__ __launch_bounds__(256) void scatter_kernel(const int* __restrict__ dag,
                                                      int* __restrict__ cursor,
                                                      int* __restrict__ perm,
                                                      int* __restrict__ dsort, int n) {
  int i = blockIdx.x * blockDim.x + threadIdx.x;
  if (i < n) {
    int d = dag[i];
    int p = atomicAdd(&cursor[d], 1);
    perm[p] = i;
    dsort[p] = d;
  }
}

// ---------------------------------------------------------------------------
// Xb[i][k] = bf16(X[perm[i]][k]) — gather X into sorted order, f32 -> bf16.
// ---------------------------------------------------------------------------
__global__ __launch_bounds__(256) void xb_conv(const float* __restrict__ X,
                                               const int* __restrict__ perm,
                                               u16* __restrict__ Xb, int n) {
  int t = blockIdx.x * 256 + threadIdx.x;
  if (t < n * 32) {               // 32 float4 groups per 128-wide row
    int row = t >> 5, kk = (t & 31) * 4;
    int src = perm[row];
    floatx4 x = *(const floatx4*)(X + (size_t)src * 128 + kk);
    s4 h;
#pragma unroll
    for (int r = 0; r < 4; ++r) h[r] = bf16bits(x[r]);
    *(s4*)(Xb + (size_t)row * 128 + kk) = h;
  }
}

// ---------------------------------------------------------------------------
// layer_gemm<K, OUTC, COLS, SEG>: Y[:, group cols] = lrelu(A @ Wt^T + b)
// - Block owns col-group of COLS; W-slice LDS-resident in MFMA-FRAGMENT ORDER:
//   region (s*NT+ni) is 1024 B; lane l holds W[colBase+ni*16+(l&15)]
//   [k = s*32+(l>>4)*8 ..+8]. af read = 64 lanes x 16 B contiguous -> zero
//   bank conflicts; all waves read same addrs -> broadcast.
// - Waves fully independent (no barriers after W load): each grabs 32-row
//   chunks from a work-steal counter; b-frags are per-lane 16 B global loads
//   (rows sorted+sequential -> 64 B segments).
// - Swapped-operand MFMA (verified r3-r6): a=weights, b=activations;
//   D: outcol = quad*4+reg (+ni*16), row = m16 (+mi*16).
// - SEG=1: per-wave bf16 scratch (32 x COLS, pitch 66) + serial dag-run walk,
//   one atomic per (run, col). dag ids broadcast via __shfl.
// ---------------------------------------------------------------------------
template <int K, int OUTC, int COLS, int SEG>
__global__ __launch_bounds__(1024) void layer_gemm(
    const u16* __restrict__ A,     // [nchunks*32][K] bf16 (sorted order)
    const u16* __restrict__ Wt,    // [OUTC][K] bf16
    const float* __restrict__ bias,
    u16* __restrict__ Y,           // SEG=0: [nchunks*32][OUTC] bf16
    float* __restrict__ segOut,    // SEG=1: [2000][256] f32
    const int* __restrict__ dsort, // SEG=1 (pre-offset)
    int* __restrict__ ctr,         // work-steal counters, one per col-group
    int nchunks, int blocksPerGroup) {
  constexpr int NT = COLS / 16;
  constexpr int NSTEP = K / 32;
  constexpr int WFRAGS = NSTEP * NT * 64;
  extern __shared__ __align__(16) char lds[];
  u16* Wl = (u16*)lds;

  const int tid  = threadIdx.x;
  const int wv   = tid >> 6;
  const int lane = tid & 63;
  const int m16  = lane & 15;
  const int quad = lane >> 4;
  const int group = blockIdx.x / blocksPerGroup;
  const int colBase = group * COLS;

  // ---- load W slice into fragment layout (once) ----
  for (int f = tid; f < WFRAGS; f += 1024) {
    int l = f & 63, reg = f >> 6;
    int s = reg / NT, ni = reg % NT;
    int col = colBase + ni * 16 + (l & 15);
    *(short8*)(Wl + (size_t)f * 8) =
        *(const short8*)(Wt + (size_t)col * K + s * 32 + (l >> 4) * 8);
  }
  __syncthreads();

  u16* Ylw = Wl + (size_t)COLS * K + wv * (32 * 66);  // SEG scratch (bf16)

  while (true) {
    int c;
    if (lane == 0) c = atomicAdd(&ctr[group], 1);
    c = __shfl(c, 0);
    if (c >= nchunks) break;
    const int r0 = c * 32;
    const u16* ap0 = A + (size_t)(r0 + m16) * K + quad * 8;
    const u16* ap1 = ap0 + (size_t)16 * K;

    floatx4 acc[NT][2];
#pragma unroll
    for (int i = 0; i < NT; i++)
#pragma unroll
      for (int j = 0; j < 2; j++) { floatx4 z = {0.f, 0.f, 0.f, 0.f}; acc[i][j] = z; }

    short8 b0 = *(const short8*)ap0;
    short8 b1 = *(const short8*)ap1;
#pragma unroll
    for (int s = 0; s < NSTEP; ++s) {
      short8 c0 = b0, c1 = b1;
      if (s + 1 < NSTEP) {
        b0 = *(const short8*)(ap0 + (s + 1) * 32);
        b1 = *(const short8*)(ap1 + (s + 1) * 32);
      }
#pragma unroll
      for (int ni = 0; ni < NT; ++ni) {
        short8 af = *(const short8*)(Wl + ((size_t)(s * NT + ni) * 64 + lane) * 8);
        acc[ni][0] = __builtin_amdgcn_mfma_f32_16x16x32_bf16(af, c0, acc[ni][0], 0, 0, 0);
        acc[ni][1] = __builtin_amdgcn_mfma_f32_16x16x32_bf16(af, c1, acc[ni][1], 0, 0, 0);
      }
    }

    if (SEG == 0) {
#pragma unroll
      for (int ni = 0; ni < NT; ++ni) {
        floatx4 bb = *(const floatx4*)&bias[colBase + ni * 16 + quad * 4];
#pragma unroll
        for (int mi = 0; mi < 2; ++mi) {
          s4 h;
#pragma unroll
          for (int r = 0; r < 4; ++r) h[r] = bf16bits(lrelu(acc[ni][mi][r] + bb[r]));
          *(s4*)&Y[(size_t)(r0 + mi * 16 + m16) * OUTC + colBase + ni * 16 + quad * 4] = h;
        }
      }
    } else {
#pragma unroll
      for (int ni = 0; ni < NT; ++ni) {
        floatx4 bb = *(const floatx4*)&bias[colBase + ni * 16 + quad * 4];
#pragma unroll
        for (int mi = 0; mi < 2; ++mi) {
          s4 h;
#pragma unroll
          for (int r = 0; r < 4; ++r) h[r] = bf16bits(lrelu(acc[ni][mi][r] + bb[r]));
          *(s4*)&Ylw[(mi * 16 + m16) * 66 + ni * 16 + quad * 4] = h;
        }
      }
      int myDag = (lane < 32) ? dsort[r0 + lane] : -1;
      float run = 0.f;
      int cur = __shfl(myDag, 0);
      for (int r = 0; r < 32; ++r) {
        int d = __shfl(myDag, r);              // wave-uniform
        float v = bits2f(Ylw[r * 66 + lane]);  // lane = col
        if (d != cur) {
          atomicAdd(&segOut[(size_t)cur * 256 + colBase + lane], run);
          run = 0.f; cur = d;
        }
        run += v;
      }
      atomicAdd(&segOut[(size_t)cur * 256 + colBase + lane], run);
    }
  }
}

// ---------------------------------------------------------------------------
// Fused 3-layer MLP for the small global stack (2000 rows) — round-6 version.
// ---------------------------------------------------------------------------
#define ROWS 32
#define H_PITCH 520
#define HBYTES (ROWS * H_PITCH * 2)
#define WL_OFF (2 * HBYTES)
#define WL_HALF 16384
#define FUSED_LDS (WL_OFF + 65536 + 128)

__device__ __forceinline__ void gload_lds16(const void* g, void* lds) {
  __builtin_amdgcn_global_load_lds(
      (const __attribute__((address_space(1))) unsigned int*)g,
      (__attribute__((address_space(3))) unsigned int*)lds, 16, 0, 0);
}

template <int K1>
__global__ __launch_bounds__(512, 2) void fused3(
    const float* __restrict__ A0, const u16* __restrict__ W1t,
    const u16* __restrict__ W2t, const u16* __restrict__ W3t,
    const float* __restrict__ b1, const float* __restrict__ b2,
    const float* __restrict__ b3, float* __restrict__ C, int M) {
  extern __shared__ __align__(16) char ldsbuf[];
  u16* H1 = (u16*)ldsbuf;
  u16* H2 = (u16*)(ldsbuf + HBYTES);
  u16* Wl = (u16*)(ldsbuf + WL_OFF);

  const int tid  = threadIdx.x;
  const int wv   = tid >> 6;
  const int lane = tid & 63;
  const int m16  = lane & 15;
  const int quad = lane >> 4;
  const int row0 = blockIdx.x * ROWS;

  const int sr  = lane >> 2;
  const int skq = ((lane & 3) - (sr >> 1)) & 3;
  const int sw8 = (m16 * 4 + ((quad + (m16 >> 1)) & 3)) * 8;

  auto stage512 = [&](const u16* Wt, int K, int k0, int sel) {
    u16* base = Wl + sel * WL_HALF;
#pragma unroll
    for (int c = 0; c < 4; ++c) {
      int chunk = wv * 4 + c;
      gload_lds16(Wt + (size_t)(chunk * 16 + sr) * K + k0 + skq * 8,
                  base + chunk * 512);
    }
  };
  auto stage256 = [&](const u16* Wt, int K, int k0, int sel) {
    u16* base = Wl + sel * 8192;
#pragma unroll
    for (int c = 0; c < 2; ++c) {
      int chunk = wv * 2 + c;
      gload_lds16(Wt + (size_t)(chunk * 16 + sr) * K + k0 + skq * 8,
                  base + chunk * 512);
    }
  };

  int grow[2];
#pragma unroll
  for (int mi = 0; mi < 2; ++mi) {
    int r = row0 + mi * 16 + m16;
    grow[mi] = r < M ? r : (M - 1);
  }
  const float* ap[2];
#pragma unroll
  for (int mi = 0; mi < 2; ++mi) ap[mi] = A0 + (size_t)grow[mi] * K1 + quad * 8;

  {  // layer 1
    constexpr int NS1 = K1 / 32;
    stage512(W1t, K1, 0, 0);
    floatx4 acc[4][2];
#pragma unroll
    for (int i = 0; i < 4; i++)
#pragma unroll
      for (int j = 0; j < 2; j++) { floatx4 z = {0.f,0.f,0.f,0.f}; acc[i][j] = z; }
#pragma unroll
    for (int s = 0; s < NS1; ++s) {
      __syncthreads();
      if (s + 1 < NS1) stage512(W1t, K1, (s + 1) * 32, (s + 1) & 1);
      const u16* wb = Wl + (s & 1) * WL_HALF;
      short8 af[4], bx[2];
#pragma unroll
      for (int ni = 0; ni < 4; ++ni)
        af[ni] = *(const short8*)(wb + (wv * 4 + ni) * 512 + sw8);
#pragma unroll
      for (int mi = 0; mi < 2; ++mi)
        bx[mi] = pack8(*(const floatx4*)(ap[mi] + s * 32),
                       *(const floatx4*)(ap[mi] + s * 32 + 4));
#pragma unroll
      for (int ni = 0; ni < 4; ++ni)
#pragma unroll
        for (int mi = 0; mi < 2; ++mi)
          acc[ni][mi] = __builtin_amdgcn_mfma_f32_16x16x32_bf16(af[ni], bx[mi], acc[ni][mi], 0, 0, 0);
    }
    const int n0 = wv * 64;
#pragma unroll
    for (int ni = 0; ni < 4; ++ni) {
      const int nb = n0 + ni * 16 + quad * 4;
      floatx4 bb = *(const floatx4*)&b1[nb];
#pragma unroll
      for (int mi = 0; mi < 2; ++mi) {
        s4 h;
#pragma unroll
        for (int r = 0; r < 4; ++r) h[r] = bf16bits(lrelu(acc[ni][mi][r] + bb[r]));
        *(s4*)&H1[(mi * 16 + m16) * H_PITCH + nb] = h;
      }
    }
  }

  {  // layer 2
    stage512(W2t, 512, 0, 0);
    const u16* hp[2];
#pragma unroll
    for (int mi = 0; mi < 2; ++mi)
      hp[mi] = H1 + (mi * 16 + m16) * H_PITCH + quad * 8;
    floatx4 acc[4][2];
#pragma unroll
    for (int i = 0; i < 4; i++)
#pragma unroll
      for (int j = 0; j < 2; j++) { floatx4 z = {0.f,0.f,0.f,0.f}; acc[i][j] = z; }
    for (int s = 0; s < 16; ++s) {
      __syncthreads();
      if (s < 15) stage512(W2t, 512, (s + 1) * 32, (s + 1) & 1);
      const u16* wb = Wl + (s & 1) * WL_HALF;
      short8 af[4], bx[2];
#pragma unroll
      for (int ni = 0; ni < 4; ++ni)
        af[ni] = *(const short8*)(wb + (wv * 4 + ni) * 512 + sw8);
#pragma unroll
      for (int mi = 0; mi < 2; ++mi) bx[mi] = *(const short8*)(hp[mi] + s * 32);
#pragma unroll
      for (int ni = 0; ni < 4; ++ni)
#pragma unroll
        for (int mi = 0; mi < 2; ++mi)
          acc[ni][mi] = __builtin_amdgcn_mfma_f32_16x16x32_bf16(af[ni], bx[mi], acc[ni][mi], 0, 0, 0);
    }
    const int n0 = wv * 64;
#pragma unroll
    for (int ni = 0; ni < 4; ++ni) {
      const int nb = n0 + ni * 16 + quad * 4;
      floatx4 bb = *(const floatx4*)&b2[nb];
#pragma unroll
      for (int mi = 0; mi < 2; ++mi) {
        s4 h;
#pragma unroll
        for (int r = 0; r < 4; ++r) h[r] = bf16bits(lrelu(acc[ni][mi][r] + bb[r]));
        *(s4*)&H2[(mi * 16 + m16) * H_PITCH + nb] = h;
      }
    }
  }

  {  // layer 3
    stage256(W3t, 512, 0, 0);
    const u16* hp[2];
#pragma unroll
    for (int mi = 0; mi < 2; ++mi)
      hp[mi] = H2 + (mi * 16 + m16) * H_PITCH + quad * 8;
    floatx4 acc[2][2];
#pragma unroll
    for (int i = 0; i < 2; i++)
#pragma unroll
      for (int j = 0; j < 2; j++) { floatx4 z = {0.f,0.f,0.f,0.f}; acc[i][j] = z; }
    for (int s = 0; s < 16; ++s) {
      __syncthreads();
      if (s < 15) stage256(W3t, 512, (s + 1) * 32, (s + 1) & 1);
      const u16* wb = Wl + (s & 1) * 8192;
      short8 af[2], bx[2];
#pragma unroll
      for (int ni = 0; ni < 2; ++ni)
        af[ni] = *(const short8*)(wb + (wv * 2 + ni) * 512 + sw8);
#pragma unroll
      for (int mi = 0; mi < 2; ++mi) bx[mi] = *(const short8*)(hp[mi] + s * 32);
#pragma unroll
      for (int ni = 0; ni < 2; ++ni)
#pragma unroll
        for (int mi = 0; mi < 2; ++mi)
          acc[ni][mi] = __builtin_amdgcn_mfma_f32_16x16x32_bf16(af[ni], bx[mi], acc[ni][mi], 0, 0, 0);
    }
    const int n0 = wv * 32;
#pragma unroll
    for (int mi = 0; mi < 2; ++mi) {
      const int r0 = row0 + mi * 16 + m16;
      if (r0 < M) {
#pragma unroll
        for (int ni = 0; ni < 2; ++ni) {
          floatx4 bb = *(const floatx4*)&b3[n0 + ni * 16 + quad * 4];
          floatx4 h;
#pragma unroll
          for (int r = 0; r < 4; ++r) h[r] = lrelu(acc[ni][mi][r] + bb[r]);
          *(floatx4*)&C[(size_t)r0 * 256 + n0 + ni * 16 + quad * 4] = h;
        }
      }
    }
  }
}

// ---------------------------------------------------------------------------
// s2[j] += chunked mask @ g3
// ---------------------------------------------------------------------------
__global__ __launch_bounds__(256) void s2_reduce(const float* __restrict__ mask,
                                                 const float* __restrict__ g3,
                                                 float* __restrict__ out,
                                                 int numDags, int outOff) {
  const int j = threadIdx.x;
  const int chunk = (numDags + gridDim.x - 1) / gridDim.x;
  const int d0 = blockIdx.x * chunk;
  const int d1 = min(d0 + chunk, numDags);
  float acc = 0.f;
  for (int d = d0; d < d1; ++d)
    acc += mask[d] * g3[(size_t)d * 256 + j];
  atomicAdd(out + outOff + j, acc);
}

extern "C" void kernel_launch(void* const* d_in, const int* in_sizes, int n_in,
                              void* d_out, int out_size, void* d_ws, size_t ws_size,
                              hipStream_t stream) {
  (void)in_sizes; (void)n_in; (void)ws_size;
  constexpr int N_   = 100000;
  constexpr int IND  = 128;
  constexpr int H1D  = 512;
  constexpr int H2D  = 512;
  constexpr int OUTD = 256;
  constexpr int NDAG = 2000;
  constexpr int CH_TOT = N_ / 32;   // 3125
  constexpr int CH_A = 1563, CH_B = CH_TOT - CH_A;  // 1562
  constexpr int ROWS_A = CH_A * 32; // 50016

  const float* X    = (const float*)d_in[0];
  const int*   dag  = (const int*)d_in[1];
  const float* mask = (const float*)d_in[2];
  const float* W1 = (const float*)d_in[3];
  const float* b1 = (const float*)d_in[4];
  const float* W2 = (const float*)d_in[5];
  const float* b2 = (const float*)d_in[6];
  const float* W3 = (const float*)d_in[7];
  const float* b3 = (const float*)d_in[8];
  const float* W4 = (const float*)d_in[9];
  const float* b4 = (const float*)d_in[10];
  const float* W5 = (const float*)d_in[11];
  const float* b5 = (const float*)d_in[12];
  const float* W6 = (const float*)d_in[13];
  const float* b6 = (const float*)d_in[14];

  char* ws = (char*)d_ws;
  auto alloc = [&](size_t bytes) {
    char* p = ws;
    ws += (bytes + 255) & ~(size_t)255;
    return p;
  };
  u16* W1t = (u16*)alloc((size_t)H1D * IND * 2);
  u16* W2t = (u16*)alloc((size_t)H2D * H1D * 2);
  u16* W3t = (u16*)alloc((size_t)OUTD * H2D * 2);
  u16* W4t = (u16*)alloc((size_t)H1D * OUTD * 2);
  u16* W5t = (u16*)alloc((size_t)H2D * H1D * 2);
  u16* W6t = (u16*)alloc((size_t)OUTD * H2D * 2);
  float* g3   = (float*)alloc((size_t)NDAG * OUTD * 4);
  int* hist   = (int*)alloc((size_t)NDAG * 4);
  int* cursor = (int*)alloc((size_t)NDAG * 4);
  int* perm   = (int*)alloc((size_t)N_ * 4);
  int* dsort  = (int*)alloc((size_t)N_ * 4);
  int* ctrs   = (int*)alloc(24 * 4);
  u16* Xb = (u16*)alloc((size_t)N_ * IND * 2);           // 25.6 MB (sorted)
  u16* Y1 = (u16*)alloc((size_t)ROWS_A * H1D * 2);       // 51.2 MB (half)
  u16* Y2 = (u16*)alloc((size_t)ROWS_A * H2D * 2);       // 51.2 MB (half)

  float* out = (float*)d_out;
  float* s1  = out;                // [2000][256] f32, output 0
  const int s2Off = NDAG * OUTD;

  constexpr int LDS_L1 = 128 * 128 * 2;                       // 32 KB
  constexpr int LDS_L2 = 128 * 512 * 2;                       // 128 KB
  constexpr int LDS_L3 = 64 * 512 * 2 + 16 * 32 * 66 * 2;     // 130 KB
  hipFuncSetAttribute(reinterpret_cast<const void*>(&layer_gemm<128, 512, 128, 0>),
                      hipFuncAttributeMaxDynamicSharedMemorySize, LDS_L1);
  hipFuncSetAttribute(reinterpret_cast<const void*>(&layer_gemm<512, 512, 128, 0>),
                      hipFuncAttributeMaxDynamicSharedMemorySize, LDS_L2);
  hipFuncSetAttribute(reinterpret_cast<const void*>(&layer_gemm<512, 256, 64, 1>),
                      hipFuncAttributeMaxDynamicSharedMemorySize, LDS_L3);
  hipFuncSetAttribute(reinterpret_cast<const void*>(&fused3<OUTD>),
                      hipFuncAttributeMaxDynamicSharedMemorySize, FUSED_LDS);

  hipMemsetAsync(out, 0, (size_t)out_size * 4, stream);
  hipMemsetAsync(hist, 0, (size_t)NDAG * 4, stream);
  hipMemsetAsync(ctrs, 0, 24 * 4, stream);

  // counting sort by dag id
  hist_kernel<<<(N_ + 255) / 256, 256, 0, stream>>>(dag, hist, N_);
  scan_offsets<<<1, 256, 0, stream>>>(hist, cursor);
  scatter_kernel<<<(N_ + 255) / 256, 256, 0, stream>>>(dag, cursor, perm, dsort, N_);

  // weight transposes + X gather/convert
  transpose_all<<<dim3(16, 16, 6), 256, 0, stream>>>(W1, W2, W3, W4, W5, W6,
                                                     W1t, W2t, W3t, W4t, W5t, W6t);
  xb_conv<<<(N_ * 32 + 255) / 256, 256, 0, stream>>>(X, perm, Xb, N_);

  // node stack, two halves (reuse Y1/Y2 buffers)
  const int BPG = 64;  // blocks per col-group -> 256 blocks total
  // half A
  layer_gemm<128, 512, 128, 0><<<256, 1024, LDS_L1, stream>>>(
      Xb, W1t, b1, Y1, nullptr, nullptr, ctrs + 0, CH_A, BPG);
  layer_gemm<512, 512, 128, 0><<<256, 1024, LDS_L2, stream>>>(
      Y1, W2t, b2, Y2, nullptr, nullptr, ctrs + 4, CH_A, BPG);
  layer_gemm<512, 256, 64, 1><<<256, 1024, LDS_L3, stream>>>(
      Y2, W3t, b3, nullptr, s1, dsort, ctrs + 8, CH_A, BPG);
  // half B
  layer_gemm<128, 512, 128, 0><<<256, 1024, LDS_L1, stream>>>(
      Xb + (size_t)ROWS_A * IND, W1t, b1, Y1, nullptr, nullptr, ctrs + 12, CH_B, BPG);
  layer_gemm<512, 512, 128, 0><<<256, 1024, LDS_L2, stream>>>(
      Y1, W2t, b2, Y2, nullptr, nullptr, ctrs + 16, CH_B, BPG);
  layer_gemm<512, 256, 64, 1><<<256, 1024, LDS_L3, stream>>>(
      Y2, W3t, b3, nullptr, s1, dsort + ROWS_A, ctrs + 20, CH_B, BPG);

  // global stack on s1 (f32 in d_out) -> g3
  fused3<OUTD><<<(NDAG + ROWS - 1) / ROWS, 512, FUSED_LDS, stream>>>(
      s1, W4t, W5t, W6t, b4, b5, b6, g3, NDAG);

  // s2 = mask @ g3 -> output 1 (pre-zeroed)
  s2_reduce<<<250, 256, 0, stream>>>(mask, g3, out, NDAG, s2Off);
}

// Round 8
// 435.854 us; speedup vs baseline: 2.3135x; 2.3135x over previous
//
#include <hip/hip_runtime.h>
#include <hip/hip_bf16.h>

typedef unsigned short u16;
typedef __attribute__((ext_vector_type(8))) short short8;
typedef __attribute__((ext_vector_type(4))) short s4;
typedef __attribute__((ext_vector_type(4))) float floatx4;

__device__ __forceinline__ float lrelu(float x) { return x > 0.f ? x : 0.01f * x; }

__device__ __forceinline__ short bf16bits(float v) {
  __hip_bfloat16 t = __float2bfloat16(v);
  return *reinterpret_cast<short*>(&t);
}
__device__ __forceinline__ float bits2f(u16 b) {
  __hip_bfloat16 t = *reinterpret_cast<__hip_bfloat16*>(&b);
  return __bfloat162float(t);
}
__device__ __forceinline__ short8 pack8(floatx4 x0, floatx4 x1) {
  short8 b;
#pragma unroll
  for (int r = 0; r < 4; ++r) { b[r] = bf16bits(x0[r]); b[4 + r] = bf16bits(x1[r]); }
  return b;
}

__device__ __forceinline__ void gload_lds16(const void* g, void* lds) {
  __builtin_amdgcn_global_load_lds(
      (const __attribute__((address_space(1))) unsigned int*)g,
      (__attribute__((address_space(3))) unsigned int*)lds, 16, 0, 0);
}

// ---------------------------------------------------------------------------
// Batched transpose+convert: 6 weights W[K][N] f32 -> Wt[N][K] bf16, 1 launch.
// ---------------------------------------------------------------------------
__global__ __launch_bounds__(256) void transpose_all(
    const float* __restrict__ W1, const float* __restrict__ W2,
    const float* __restrict__ W3, const float* __restrict__ W4,
    const float* __restrict__ W5, const float* __restrict__ W6,
    u16* __restrict__ T1, u16* __restrict__ T2, u16* __restrict__ T3,
    u16* __restrict__ T4, u16* __restrict__ T5, u16* __restrict__ T6) {
  const float* W; u16* T; int K, N;
  switch (blockIdx.z) {
    case 0: W = W1; T = T1; K = 128; N = 512; break;
    case 1: W = W2; T = T2; K = 512; N = 512; break;
    case 2: W = W3; T = T3; K = 512; N = 256; break;
    case 3: W = W4; T = T4; K = 256; N = 512; break;
    case 4: W = W5; T = T5; K = 512; N = 512; break;
    default: W = W6; T = T6; K = 512; N = 256; break;
  }
  if ((int)blockIdx.x >= N / 32 || (int)blockIdx.y >= K / 32) return;
  __shared__ u16 tile[32][33];
  const int tx = threadIdx.x & 31;
  const int ty = threadIdx.x >> 5;
  const int n0 = blockIdx.x * 32;
  const int k0 = blockIdx.y * 32;
  for (int i = ty; i < 32; i += 8)
    tile[i][tx] = (u16)bf16bits(W[(size_t)(k0 + i) * N + n0 + tx]);
  __syncthreads();
  for (int i = ty; i < 32; i += 8)
    T[(size_t)(n0 + i) * K + k0 + tx] = tile[tx][i];
}

// ---------------------------------------------------------------------------
// Counting sort of node ids by dag id (2000 bins).
// ---------------------------------------------------------------------------
__global__ __launch_bounds__(256) void hist_kernel(const int* __restrict__ dag,
                                                   int* __restrict__ hist, int n) {
  int i = blockIdx.x * blockDim.x + threadIdx.x;
  if (i < n) atomicAdd(&hist[dag[i]], 1);
}

__global__ __launch_bounds__(256) void scan_offsets(const int* __restrict__ hist,
                                                    int* __restrict__ cursor) {
  __shared__ int part[256];
  const int t = threadIdx.x;
  const int base = t * 8;
  int loc[8];
  int s = 0;
#pragma unroll
  for (int j = 0; j < 8; ++j) {
    int v = (base + j < 2000) ? hist[base + j] : 0;
    loc[j] = s;
    s += v;
  }
  part[t] = s;
  __syncthreads();
  int val = s;
  for (int off = 1; off < 256; off <<= 1) {
    int tmp = (t >= off) ? part[t - off] : 0;
    __syncthreads();
    val += tmp;
    part[t] = val;
    __syncthreads();
  }
  const int chunkBase = (t == 0) ? 0 : part[t - 1];
#pragma unroll
  for (int j = 0; j < 8; ++j)
    if (base + j < 2000) cursor[base + j] = chunkBase + loc[j];
}

__global__ __launch_bounds__(256) void scatter_kernel(const int* __restrict__ dag,
                                                      int* __restrict__ cursor,
                                                      int* __restrict__ perm,
                                                      int* __restrict__ dsort, int n) {
  int i = blockIdx.x * blockDim.x + threadIdx.x;
  if (i < n) {
    int d = dag[i];
    int p = atomicAdd(&cursor[d], 1);
    perm[p] = i;
    dsort[p] = d;
  }
}

// ---------------------------------------------------------------------------
// Xb[i][k] = bf16(X[perm[i]][k]) — gather X into sorted order, f32 -> bf16.
// ---------------------------------------------------------------------------
__global__ __launch_bounds__(256) void xb_conv(const float* __restrict__ X,
                                               const int* __restrict__ perm,
                                               u16* __restrict__ Xb, int n) {
  int t = blockIdx.x * 256 + threadIdx.x;
  if (t < n * 32) {
    int row = t >> 5, kk = (t & 31) * 4;
    int src = perm[row];
    floatx4 x = *(const floatx4*)(X + (size_t)src * 128 + kk);
    s4 h;
#pragma unroll
    for (int r = 0; r < 4; ++r) h[r] = bf16bits(x[r]);
    *(s4*)(Xb + (size_t)row * 128 + kk) = h;
  }
}

// ---------------------------------------------------------------------------
// m97-style GEMM: C[128x128 tile] = lrelu(A @ Wt^T + bias).
// A[Mpad][K] bf16 (dag-sorted rows), Wt[N][K] bf16. 256 thr / 4 waves,
// BK=32, single-buffered LDS (As 8KB + Bs 8KB), global_load_lds width-16.
// Verified operand convention (r3-r6): mfma(wf, bx, acc) -> D: col=quad*4+reg,
// row=lane&15.
// SEG=0: Y[row][col] bf16.  SEG=1: per-wave 64x64 scratch + segmented dag walk,
// one f32 atomic per (dag-run, col); padded rows carry dsort=-1 -> skipped.
// ---------------------------------------------------------------------------
template <int K, int N, int SEG>
__global__ __launch_bounds__(256, 3) void layer_gemm(
    const u16* __restrict__ A, const u16* __restrict__ Wt,
    const float* __restrict__ bias, u16* __restrict__ Y,
    float* __restrict__ segOut, const int* __restrict__ dsort) {
  extern __shared__ __align__(16) char lds[];
  u16* As = (u16*)lds;            // 8 chunks x 512 u16 (16 rows x 32 k each)
  u16* Bs = (u16*)(lds + 8192);

  const int tid  = threadIdx.x;
  const int wid  = tid >> 6;
  const int lane = tid & 63;
  const int m16  = lane & 15;
  const int quad = lane >> 4;
  const int row0 = blockIdx.x * 128;
  const int col0 = blockIdx.y * 128;

  const int sr = lane >> 2;        // staging row within 16-row chunk
  const int sk = (lane & 3) * 8;   // staging k offset (elements)
  const int c0 = wid * 2, c1 = c0 + 1;
  const int waveM = (wid >> 1) * 64;
  const int waveN = (wid & 1) * 64;

  const u16* Aw0 = A + (size_t)(row0 + c0 * 16 + sr) * K + sk;
  const u16* Aw1 = A + (size_t)(row0 + c1 * 16 + sr) * K + sk;
  const u16* Bw0 = Wt + (size_t)(col0 + c0 * 16 + sr) * K + sk;
  const u16* Bw1 = Wt + (size_t)(col0 + c1 * 16 + sr) * K + sk;

  floatx4 acc[4][4];
#pragma unroll
  for (int i = 0; i < 4; i++)
#pragma unroll
    for (int j = 0; j < 4; j++) { floatx4 z = {0.f, 0.f, 0.f, 0.f}; acc[i][j] = z; }

  for (int k0 = 0; k0 < K; k0 += 32) {
    gload_lds16(Aw0 + k0, As + c0 * 512);
    gload_lds16(Aw1 + k0, As + c1 * 512);
    gload_lds16(Bw0 + k0, Bs + c0 * 512);
    gload_lds16(Bw1 + k0, Bs + c1 * 512);
    __syncthreads();
    short8 wf[4], bx[4];
#pragma unroll
    for (int ni = 0; ni < 4; ++ni)
      wf[ni] = *(const short8*)&Bs[((waveN >> 4) + ni) * 512 + m16 * 32 + quad * 8];
#pragma unroll
    for (int mi = 0; mi < 4; ++mi)
      bx[mi] = *(const short8*)&As[((waveM >> 4) + mi) * 512 + m16 * 32 + quad * 8];
#pragma unroll
    for (int ni = 0; ni < 4; ++ni)
#pragma unroll
      for (int mi = 0; mi < 4; ++mi)
        acc[ni][mi] = __builtin_amdgcn_mfma_f32_16x16x32_bf16(wf[ni], bx[mi], acc[ni][mi], 0, 0, 0);
    __syncthreads();
  }

  if (SEG == 0) {
#pragma unroll
    for (int ni = 0; ni < 4; ++ni) {
      floatx4 bb = *(const floatx4*)&bias[col0 + waveN + ni * 16 + quad * 4];
#pragma unroll
      for (int mi = 0; mi < 4; ++mi) {
        s4 h;
#pragma unroll
        for (int r = 0; r < 4; ++r) h[r] = bf16bits(lrelu(acc[ni][mi][r] + bb[r]));
        *(s4*)&Y[(size_t)(row0 + waveM + mi * 16 + m16) * N +
                 col0 + waveN + ni * 16 + quad * 4] = h;
      }
    }
  } else {
    // per-wave 64x64 bf16 scratch, pitch 68 (8B-aligned rows, bank rotation)
    u16* Yw = (u16*)(lds + 16384) + wid * (64 * 68);
#pragma unroll
    for (int ni = 0; ni < 4; ++ni) {
      floatx4 bb = *(const floatx4*)&bias[col0 + waveN + ni * 16 + quad * 4];
#pragma unroll
      for (int mi = 0; mi < 4; ++mi) {
        s4 h;
#pragma unroll
        for (int r = 0; r < 4; ++r) h[r] = bf16bits(lrelu(acc[ni][mi][r] + bb[r]));
        *(s4*)&Yw[(mi * 16 + m16) * 68 + ni * 16 + quad * 4] = h;
      }
    }
    const int myDag = dsort[row0 + waveM + lane];  // lane r holds row r's dag
    float run = 0.f;
    int cur = __shfl(myDag, 0);
    for (int r = 0; r < 64; ++r) {
      int d = __shfl(myDag, r);                 // wave-uniform
      float v = bits2f(Yw[r * 68 + lane]);      // lane = local col
      if (d != cur) {
        if (cur >= 0) atomicAdd(&segOut[(size_t)cur * 256 + col0 + waveN + lane], run);
        run = 0.f; cur = d;
      }
      run += v;
    }
    if (cur >= 0) atomicAdd(&segOut[(size_t)cur * 256 + col0 + waveN + lane], run);
  }
}

// ---------------------------------------------------------------------------
// Fused 3-layer MLP for the small global stack (2000 rows) — round-6 version.
// ---------------------------------------------------------------------------
#define ROWS 32
#define H_PITCH 520
#define HBYTES (ROWS * H_PITCH * 2)
#define WL_OFF (2 * HBYTES)
#define WL_HALF 16384
#define FUSED_LDS (WL_OFF + 65536 + 128)

template <int K1>
__global__ __launch_bounds__(512, 2) void fused3(
    const float* __restrict__ A0, const u16* __restrict__ W1t,
    const u16* __restrict__ W2t, const u16* __restrict__ W3t,
    const float* __restrict__ b1, const float* __restrict__ b2,
    const float* __restrict__ b3, float* __restrict__ C, int M) {
  extern __shared__ __align__(16) char ldsbuf[];
  u16* H1 = (u16*)ldsbuf;
  u16* H2 = (u16*)(ldsbuf + HBYTES);
  u16* Wl = (u16*)(ldsbuf + WL_OFF);

  const int tid  = threadIdx.x;
  const int wv   = tid >> 6;
  const int lane = tid & 63;
  const int m16  = lane & 15;
  const int quad = lane >> 4;
  const int row0 = blockIdx.x * ROWS;

  const int sr  = lane >> 2;
  const int skq = ((lane & 3) - (sr >> 1)) & 3;
  const int sw8 = (m16 * 4 + ((quad + (m16 >> 1)) & 3)) * 8;

  auto stage512 = [&](const u16* Wt, int K, int k0, int sel) {
    u16* base = Wl + sel * WL_HALF;
#pragma unroll
    for (int c = 0; c < 4; ++c) {
      int chunk = wv * 4 + c;
      gload_lds16(Wt + (size_t)(chunk * 16 + sr) * K + k0 + skq * 8,
                  base + chunk * 512);
    }
  };
  auto stage256 = [&](const u16* Wt, int K, int k0, int sel) {
    u16* base = Wl + sel * 8192;
#pragma unroll
    for (int c = 0; c < 2; ++c) {
      int chunk = wv * 2 + c;
      gload_lds16(Wt + (size_t)(chunk * 16 + sr) * K + k0 + skq * 8,
                  base + chunk * 512);
    }
  };

  int grow[2];
#pragma unroll
  for (int mi = 0; mi < 2; ++mi) {
    int r = row0 + mi * 16 + m16;
    grow[mi] = r < M ? r : (M - 1);
  }
  const float* ap[2];
#pragma unroll
  for (int mi = 0; mi < 2; ++mi) ap[mi] = A0 + (size_t)grow[mi] * K1 + quad * 8;

  {  // layer 1
    constexpr int NS1 = K1 / 32;
    stage512(W1t, K1, 0, 0);
    floatx4 acc[4][2];
#pragma unroll
    for (int i = 0; i < 4; i++)
#pragma unroll
      for (int j = 0; j < 2; j++) { floatx4 z = {0.f,0.f,0.f,0.f}; acc[i][j] = z; }
#pragma unroll
    for (int s = 0; s < NS1; ++s) {
      __syncthreads();
      if (s + 1 < NS1) stage512(W1t, K1, (s + 1) * 32, (s + 1) & 1);
      const u16* wb = Wl + (s & 1) * WL_HALF;
      short8 af[4], bx[2];
#pragma unroll
      for (int ni = 0; ni < 4; ++ni)
        af[ni] = *(const short8*)(wb + (wv * 4 + ni) * 512 + sw8);
#pragma unroll
      for (int mi = 0; mi < 2; ++mi)
        bx[mi] = pack8(*(const floatx4*)(ap[mi] + s * 32),
                       *(const floatx4*)(ap[mi] + s * 32 + 4));
#pragma unroll
      for (int ni = 0; ni < 4; ++ni)
#pragma unroll
        for (int mi = 0; mi < 2; ++mi)
          acc[ni][mi] = __builtin_amdgcn_mfma_f32_16x16x32_bf16(af[ni], bx[mi], acc[ni][mi], 0, 0, 0);
    }
    const int n0 = wv * 64;
#pragma unroll
    for (int ni = 0; ni < 4; ++ni) {
      const int nb = n0 + ni * 16 + quad * 4;
      floatx4 bb = *(const floatx4*)&b1[nb];
#pragma unroll
      for (int mi = 0; mi < 2; ++mi) {
        s4 h;
#pragma unroll
        for (int r = 0; r < 4; ++r) h[r] = bf16bits(lrelu(acc[ni][mi][r] + bb[r]));
        *(s4*)&H1[(mi * 16 + m16) * H_PITCH + nb] = h;
      }
    }
  }

  {  // layer 2
    stage512(W2t, 512, 0, 0);
    const u16* hp[2];
#pragma unroll
    for (int mi = 0; mi < 2; ++mi)
      hp[mi] = H1 + (mi * 16 + m16) * H_PITCH + quad * 8;
    floatx4 acc[4][2];
#pragma unroll
    for (int i = 0; i < 4; i++)
#pragma unroll
      for (int j = 0; j < 2; j++) { floatx4 z = {0.f,0.f,0.f,0.f}; acc[i][j] = z; }
    for (int s = 0; s < 16; ++s) {
      __syncthreads();
      if (s < 15) stage512(W2t, 512, (s + 1) * 32, (s + 1) & 1);
      const u16* wb = Wl + (s & 1) * WL_HALF;
      short8 af[4], bx[2];
#pragma unroll
      for (int ni = 0; ni < 4; ++ni)
        af[ni] = *(const short8*)(wb + (wv * 4 + ni) * 512 + sw8);
#pragma unroll
      for (int mi = 0; mi < 2; ++mi) bx[mi] = *(const short8*)(hp[mi] + s * 32);
#pragma unroll
      for (int ni = 0; ni < 4; ++ni)
#pragma unroll
        for (int mi = 0; mi < 2; ++mi)
          acc[ni][mi] = __builtin_amdgcn_mfma_f32_16x16x32_bf16(af[ni], bx[mi], acc[ni][mi], 0, 0, 0);
    }
    const int n0 = wv * 64;
#pragma unroll
    for (int ni = 0; ni < 4; ++ni) {
      const int nb = n0 + ni * 16 + quad * 4;
      floatx4 bb = *(const floatx4*)&b2[nb];
#pragma unroll
      for (int mi = 0; mi < 2; ++mi) {
        s4 h;
#pragma unroll
        for (int r = 0; r < 4; ++r) h[r] = bf16bits(lrelu(acc[ni][mi][r] + bb[r]));
        *(s4*)&H2[(mi * 16 + m16) * H_PITCH + nb] = h;
      }
    }
  }

  {  // layer 3
    stage256(W3t, 512, 0, 0);
    const u16* hp[2];
#pragma unroll
    for (int mi = 0; mi < 2; ++mi)
      hp[mi] = H2 + (mi * 16 + m16) * H_PITCH + quad * 8;
    floatx4 acc[2][2];
#pragma unroll
    for (int i = 0; i < 2; i++)
#pragma unroll
      for (int j = 0; j < 2; j++) { floatx4 z = {0.f,0.f,0.f,0.f}; acc[i][j] = z; }
    for (int s = 0; s < 16; ++s) {
      __syncthreads();
      if (s < 15) stage256(W3t, 512, (s + 1) * 32, (s + 1) & 1);
      const u16* wb = Wl + (s & 1) * 8192;
      short8 af[2], bx[2];
#pragma unroll
      for (int ni = 0; ni < 2; ++ni)
        af[ni] = *(const short8*)(wb + (wv * 2 + ni) * 512 + sw8);
#pragma unroll
      for (int mi = 0; mi < 2; ++mi) bx[mi] = *(const short8*)(hp[mi] + s * 32);
#pragma unroll
      for (int ni = 0; ni < 2; ++ni)
#pragma unroll
        for (int mi = 0; mi < 2; ++mi)
          acc[ni][mi] = __builtin_amdgcn_mfma_f32_16x16x32_bf16(af[ni], bx[mi], acc[ni][mi], 0, 0, 0);
    }
    const int n0 = wv * 32;
#pragma unroll
    for (int mi = 0; mi < 2; ++mi) {
      const int r0 = row0 + mi * 16 + m16;
      if (r0 < M) {
#pragma unroll
        for (int ni = 0; ni < 2; ++ni) {
          floatx4 bb = *(const floatx4*)&b3[n0 + ni * 16 + quad * 4];
          floatx4 h;
#pragma unroll
          for (int r = 0; r < 4; ++r) h[r] = lrelu(acc[ni][mi][r] + bb[r]);
          *(floatx4*)&C[(size_t)r0 * 256 + n0 + ni * 16 + quad * 4] = h;
        }
      }
    }
  }
}

// ---------------------------------------------------------------------------
// s2[j] += chunked mask @ g3
// ---------------------------------------------------------------------------
__global__ __launch_bounds__(256) void s2_reduce(const float* __restrict__ mask,
                                                 const float* __restrict__ g3,
                                                 float* __restrict__ out,
                                                 int numDags, int outOff) {
  const int j = threadIdx.x;
  const int chunk = (numDags + gridDim.x - 1) / gridDim.x;
  const int d0 = blockIdx.x * chunk;
  const int d1 = min(d0 + chunk, numDags);
  float acc = 0.f;
  for (int d = d0; d < d1; ++d)
    acc += mask[d] * g3[(size_t)d * 256 + j];
  atomicAdd(out + outOff + j, acc);
}

extern "C" void kernel_launch(void* const* d_in, const int* in_sizes, int n_in,
                              void* d_out, int out_size, void* d_ws, size_t ws_size,
                              hipStream_t stream) {
  (void)in_sizes; (void)n_in; (void)ws_size;
  constexpr int N_   = 100000;
  constexpr int MPAD = 100096;               // 782 * 128
  constexpr int HM   = MPAD / 2;             // 50048 = 391 * 128
  constexpr int IND  = 128;
  constexpr int H1D  = 512;
  constexpr int H2D  = 512;
  constexpr int OUTD = 256;
  constexpr int NDAG = 2000;

  const float* X    = (const float*)d_in[0];
  const int*   dag  = (const int*)d_in[1];
  const float* mask = (const float*)d_in[2];
  const float* W1 = (const float*)d_in[3];
  const float* b1 = (const float*)d_in[4];
  const float* W2 = (const float*)d_in[5];
  const float* b2 = (const float*)d_in[6];
  const float* W3 = (const float*)d_in[7];
  const float* b3 = (const float*)d_in[8];
  const float* W4 = (const float*)d_in[9];
  const float* b4 = (const float*)d_in[10];
  const float* W5 = (const float*)d_in[11];
  const float* b5 = (const float*)d_in[12];
  const float* W6 = (const float*)d_in[13];
  const float* b6 = (const float*)d_in[14];

  char* ws = (char*)d_ws;
  auto alloc = [&](size_t bytes) {
    char* p = ws;
    ws += (bytes + 255) & ~(size_t)255;
    return p;
  };
  u16* W1t = (u16*)alloc((size_t)H1D * IND * 2);
  u16* W2t = (u16*)alloc((size_t)H2D * H1D * 2);
  u16* W3t = (u16*)alloc((size_t)OUTD * H2D * 2);
  u16* W4t = (u16*)alloc((size_t)H1D * OUTD * 2);
  u16* W5t = (u16*)alloc((size_t)H2D * H1D * 2);
  u16* W6t = (u16*)alloc((size_t)OUTD * H2D * 2);
  float* g3   = (float*)alloc((size_t)NDAG * OUTD * 4);
  int* hist   = (int*)alloc((size_t)NDAG * 4);
  int* cursor = (int*)alloc((size_t)NDAG * 4);
  int* perm   = (int*)alloc((size_t)N_ * 4);
  int* dsort  = (int*)alloc((size_t)MPAD * 4);
  u16* Xb = (u16*)alloc((size_t)MPAD * IND * 2);   // 25.6 MB (sorted, padded)
  u16* Y1 = (u16*)alloc((size_t)HM * H1D * 2);     // 51.2 MB (half)
  u16* Y2 = (u16*)alloc((size_t)HM * H2D * 2);     // 51.2 MB (half)

  float* out = (float*)d_out;
  float* s1  = out;                // [2000][256] f32, output 0
  const int s2Off = NDAG * OUTD;

  constexpr int LDS_GEMM = 16384;
  constexpr int LDS_SEG  = 16384 + 4 * 64 * 68 * 2;  // 51200
  hipFuncSetAttribute(reinterpret_cast<const void*>(&layer_gemm<128, 512, 0>),
                      hipFuncAttributeMaxDynamicSharedMemorySize, LDS_GEMM);
  hipFuncSetAttribute(reinterpret_cast<const void*>(&layer_gemm<512, 512, 0>),
                      hipFuncAttributeMaxDynamicSharedMemorySize, LDS_GEMM);
  hipFuncSetAttribute(reinterpret_cast<const void*>(&layer_gemm<512, 256, 1>),
                      hipFuncAttributeMaxDynamicSharedMemorySize, LDS_SEG);
  hipFuncSetAttribute(reinterpret_cast<const void*>(&fused3<OUTD>),
                      hipFuncAttributeMaxDynamicSharedMemorySize, FUSED_LDS);

  hipMemsetAsync(out, 0, (size_t)out_size * 4, stream);
  hipMemsetAsync(hist, 0, (size_t)NDAG * 4, stream);
  hipMemsetAsync(dsort + N_, 0xFF, (size_t)(MPAD - N_) * 4, stream);   // -1 tail
  hipMemsetAsync(Xb + (size_t)N_ * IND, 0, (size_t)(MPAD - N_) * IND * 2, stream);

  // counting sort by dag id
  hist_kernel<<<(N_ + 255) / 256, 256, 0, stream>>>(dag, hist, N_);
  scan_offsets<<<1, 256, 0, stream>>>(hist, cursor);
  scatter_kernel<<<(N_ + 255) / 256, 256, 0, stream>>>(dag, cursor, perm, dsort, N_);

  // weight transposes + X gather/convert
  transpose_all<<<dim3(16, 16, 6), 256, 0, stream>>>(W1, W2, W3, W4, W5, W6,
                                                     W1t, W2t, W3t, W4t, W5t, W6t);
  xb_conv<<<(N_ * 32 + 255) / 256, 256, 0, stream>>>(X, perm, Xb, N_);

  // node stack, two 50048-row halves (Y1/Y2 reused)
  for (int h = 0; h < 2; ++h) {
    const size_t ro = (size_t)h * HM;
    layer_gemm<128, 512, 0><<<dim3(HM / 128, 4), 256, LDS_GEMM, stream>>>(
        Xb + ro * IND, W1t, b1, Y1, nullptr, nullptr);
    layer_gemm<512, 512, 0><<<dim3(HM / 128, 4), 256, LDS_GEMM, stream>>>(
        Y1, W2t, b2, Y2, nullptr, nullptr);
    layer_gemm<512, 256, 1><<<dim3(HM / 128, 2), 256, LDS_SEG, stream>>>(
        Y2, W3t, b3, nullptr, s1, dsort + ro);
  }

  // global stack on s1 (f32 in d_out) -> g3
  fused3<OUTD><<<(NDAG + ROWS - 1) / ROWS, 512, FUSED_LDS, stream>>>(
      s1, W4t, W5t, W6t, b4, b5, b6, g3, NDAG);

  // s2 = mask @ g3 -> output 1 (pre-zeroed)
  s2_reduce<<<250, 256, 0, stream>>>(mask, g3, out, NDAG, s2Off);
}

// Round 9
// 383.074 us; speedup vs baseline: 2.6322x; 1.1378x over previous
//
#include <hip/hip_runtime.h>
#include <hip/hip_bf16.h>

typedef unsigned short u16;
typedef __attribute__((ext_vector_type(8))) short short8;
typedef __attribute__((ext_vector_type(4))) short s4;
typedef __attribute__((ext_vector_type(4))) float floatx4;

__device__ __forceinline__ float lrelu(float x) { return x > 0.f ? x : 0.01f * x; }

__device__ __forceinline__ short bf16bits(float v) {
  __hip_bfloat16 t = __float2bfloat16(v);
  return *reinterpret_cast<short*>(&t);
}
__device__ __forceinline__ float bits2f(u16 b) {
  __hip_bfloat16 t = *reinterpret_cast<__hip_bfloat16*>(&b);
  return __bfloat162float(t);
}
__device__ __forceinline__ short8 pack8(floatx4 x0, floatx4 x1) {
  short8 b;
#pragma unroll
  for (int r = 0; r < 4; ++r) { b[r] = bf16bits(x0[r]); b[4 + r] = bf16bits(x1[r]); }
  return b;
}

__device__ __forceinline__ void gload_lds16(const void* g, void* lds) {
  __builtin_amdgcn_global_load_lds(
      (const __attribute__((address_space(1))) unsigned int*)g,
      (__attribute__((address_space(3))) unsigned int*)lds, 16, 0, 0);
}

// ---------------------------------------------------------------------------
// Batched transpose+convert: 6 weights W[K][N] f32 -> Wt[N][K] bf16, 1 launch.
// ---------------------------------------------------------------------------
__global__ __launch_bounds__(256) void transpose_all(
    const float* __restrict__ W1, const float* __restrict__ W2,
    const float* __restrict__ W3, const float* __restrict__ W4,
    const float* __restrict__ W5, const float* __restrict__ W6,
    u16* __restrict__ T1, u16* __restrict__ T2, u16* __restrict__ T3,
    u16* __restrict__ T4, u16* __restrict__ T5, u16* __restrict__ T6) {
  const float* W; u16* T; int K, N;
  switch (blockIdx.z) {
    case 0: W = W1; T = T1; K = 128; N = 512; break;
    case 1: W = W2; T = T2; K = 512; N = 512; break;
    case 2: W = W3; T = T3; K = 512; N = 256; break;
    case 3: W = W4; T = T4; K = 256; N = 512; break;
    case 4: W = W5; T = T5; K = 512; N = 512; break;
    default: W = W6; T = T6; K = 512; N = 256; break;
  }
  if ((int)blockIdx.x >= N / 32 || (int)blockIdx.y >= K / 32) return;
  __shared__ u16 tile[32][33];
  const int tx = threadIdx.x & 31;
  const int ty = threadIdx.x >> 5;
  const int n0 = blockIdx.x * 32;
  const int k0 = blockIdx.y * 32;
  for (int i = ty; i < 32; i += 8)
    tile[i][tx] = (u16)bf16bits(W[(size_t)(k0 + i) * N + n0 + tx]);
  __syncthreads();
  for (int i = ty; i < 32; i += 8)
    T[(size_t)(n0 + i) * K + k0 + tx] = tile[tx][i];
}

// ---------------------------------------------------------------------------
// Counting sort of node ids by dag id (2000 bins).
// ---------------------------------------------------------------------------
__global__ __launch_bounds__(256) void hist_kernel(const int* __restrict__ dag,
                                                   int* __restrict__ hist, int n) {
  int i = blockIdx.x * blockDim.x + threadIdx.x;
  if (i < n) atomicAdd(&hist[dag[i]], 1);
}

__global__ __launch_bounds__(256) void scan_offsets(const int* __restrict__ hist,
                                                    int* __restrict__ cursor) {
  __shared__ int part[256];
  const int t = threadIdx.x;
  const int base = t * 8;
  int loc[8];
  int s = 0;
#pragma unroll
  for (int j = 0; j < 8; ++j) {
    int v = (base + j < 2000) ? hist[base + j] : 0;
    loc[j] = s;
    s += v;
  }
  part[t] = s;
  __syncthreads();
  int val = s;
  for (int off = 1; off < 256; off <<= 1) {
    int tmp = (t >= off) ? part[t - off] : 0;
    __syncthreads();
    val += tmp;
    part[t] = val;
    __syncthreads();
  }
  const int chunkBase = (t == 0) ? 0 : part[t - 1];
#pragma unroll
  for (int j = 0; j < 8; ++j)
    if (base + j < 2000) cursor[base + j] = chunkBase + loc[j];
}

__global__ __launch_bounds__(256) void scatter_kernel(const int* __restrict__ dag,
                                                      int* __restrict__ cursor,
                                                      int* __restrict__ perm,
                                                      int* __restrict__ dsort, int n) {
  int i = blockIdx.x * blockDim.x + threadIdx.x;
  if (i < n) {
    int d = dag[i];
    int p = atomicAdd(&cursor[d], 1);
    perm[p] = i;
    dsort[p] = d;
  }
}

// ---------------------------------------------------------------------------
// Xb[i][k] = bf16(X[perm[i]][k]) — gather X into sorted order, f32 -> bf16.
// ---------------------------------------------------------------------------
__global__ __launch_bounds__(256) void xb_conv(const float* __restrict__ X,
                                               const int* __restrict__ perm,
                                               u16* __restrict__ Xb, int n) {
  int t = blockIdx.x * 256 + threadIdx.x;
  if (t < n * 32) {
    int row = t >> 5, kk = (t & 31) * 4;
    int src = perm[row];
    floatx4 x = *(const floatx4*)(X + (size_t)src * 128 + kk);
    s4 h;
#pragma unroll
    for (int r = 0; r < 4; ++r) h[r] = bf16bits(x[r]);
    *(s4*)(Xb + (size_t)row * 128 + kk) = h;
  }
}

// ---------------------------------------------------------------------------
// m97-style GEMM, BK=64 (two 32-k panels per stage), col-group = blockIdx.x
// (FAST dim -> A-tile L3 reuse across col-groups). 256 thr / 4 waves,
// tile 128x128. As/Bs: [panel][8 chunks][16 rows x 32 k] = 16 KB each.
// Operand convention (verified r3-r8): mfma(wf, bx, acc) -> D: col=quad*4+reg,
// row=lane&15.
// SEG=0: Y bf16. SEG=1: per-wave 64x64 scratch (overlaps dead staging LDS)
// + segmented dag walk, one f32 atomic per (dag-run, col); dsort=-1 skipped.
// ---------------------------------------------------------------------------
template <int K, int N, int SEG>
__global__ __launch_bounds__(256, 4) void layer_gemm(
    const u16* __restrict__ A, const u16* __restrict__ Wt,
    const float* __restrict__ bias, u16* __restrict__ Y,
    float* __restrict__ segOut, const int* __restrict__ dsort) {
  extern __shared__ __align__(16) char lds[];
  u16* As = (u16*)lds;              // [2][8][512]
  u16* Bs = (u16*)(lds + 16384);    // [2][8][512]

  const int tid  = threadIdx.x;
  const int wid  = tid >> 6;
  const int lane = tid & 63;
  const int m16  = lane & 15;
  const int quad = lane >> 4;
  const int col0 = blockIdx.x * 128;   // col-group fast
  const int row0 = blockIdx.y * 128;

  const int sr = lane >> 2;
  const int sk = (lane & 3) * 8;
  const int waveM = (wid >> 1) * 64;
  const int waveN = (wid & 1) * 64;
  const int mch = (wid >> 1) * 4;      // A chunk base for frag reads
  const int nch = (wid & 1) * 4;       // B chunk base

  floatx4 acc[4][4];
#pragma unroll
  for (int i = 0; i < 4; i++)
#pragma unroll
    for (int j = 0; j < 4; j++) { floatx4 z = {0.f, 0.f, 0.f, 0.f}; acc[i][j] = z; }

  for (int k0 = 0; k0 < K; k0 += 64) {
    // stage 2 panels x (A chunks 2w,2w+1 + B chunks 2w,2w+1) per wave
#pragma unroll
    for (int p = 0; p < 2; ++p)
#pragma unroll
      for (int c = 0; c < 2; ++c) {
        const int ch = wid * 2 + c;
        gload_lds16(A + (size_t)(row0 + ch * 16 + sr) * K + k0 + p * 32 + sk,
                    As + p * 4096 + ch * 512);
        gload_lds16(Wt + (size_t)(col0 + ch * 16 + sr) * K + k0 + p * 32 + sk,
                    Bs + p * 4096 + ch * 512);
      }
    __syncthreads();
#pragma unroll
    for (int p = 0; p < 2; ++p) {
      short8 wf[4], bx[4];
#pragma unroll
      for (int ni = 0; ni < 4; ++ni)
        wf[ni] = *(const short8*)&Bs[p * 4096 + (nch + ni) * 512 + m16 * 32 + quad * 8];
#pragma unroll
      for (int mi = 0; mi < 4; ++mi)
        bx[mi] = *(const short8*)&As[p * 4096 + (mch + mi) * 512 + m16 * 32 + quad * 8];
#pragma unroll
      for (int ni = 0; ni < 4; ++ni)
#pragma unroll
        for (int mi = 0; mi < 4; ++mi)
          acc[ni][mi] = __builtin_amdgcn_mfma_f32_16x16x32_bf16(wf[ni], bx[mi], acc[ni][mi], 0, 0, 0);
    }
    __syncthreads();
  }

  if (SEG == 0) {
#pragma unroll
    for (int ni = 0; ni < 4; ++ni) {
      floatx4 bb = *(const floatx4*)&bias[col0 + waveN + ni * 16 + quad * 4];
#pragma unroll
      for (int mi = 0; mi < 4; ++mi) {
        s4 h;
#pragma unroll
        for (int r = 0; r < 4; ++r) h[r] = bf16bits(lrelu(acc[ni][mi][r] + bb[r]));
        *(s4*)&Y[(size_t)(row0 + waveM + mi * 16 + m16) * N +
                 col0 + waveN + ni * 16 + quad * 4] = h;
      }
    }
  } else {
    // per-wave 64x64 bf16 scratch (pitch 68), overlapping dead staging LDS
    u16* Yw = (u16*)lds + wid * (64 * 68);
#pragma unroll
    for (int ni = 0; ni < 4; ++ni) {
      floatx4 bb = *(const floatx4*)&bias[col0 + waveN + ni * 16 + quad * 4];
#pragma unroll
      for (int mi = 0; mi < 4; ++mi) {
        s4 h;
#pragma unroll
        for (int r = 0; r < 4; ++r) h[r] = bf16bits(lrelu(acc[ni][mi][r] + bb[r]));
        *(s4*)&Yw[(mi * 16 + m16) * 68 + ni * 16 + quad * 4] = h;
      }
    }
    const int myDag = dsort[row0 + waveM + lane];
    float run = 0.f;
    int cur = __shfl(myDag, 0);
    for (int r = 0; r < 64; ++r) {
      int d = __shfl(myDag, r);                 // wave-uniform
      float v = bits2f(Yw[r * 68 + lane]);      // lane = local col
      if (d != cur) {
        if (cur >= 0) atomicAdd(&segOut[(size_t)cur * 256 + col0 + waveN + lane], run);
        run = 0.f; cur = d;
      }
      run += v;
    }
    if (cur >= 0) atomicAdd(&segOut[(size_t)cur * 256 + col0 + waveN + lane], run);
  }
}

// ---------------------------------------------------------------------------
// Fused 3-layer global stack (2000 rows) + fused s2 = mask @ g3 reduction.
// g3 never materialized: each block reduces mask-weighted layer-3 outputs
// over its 32 rows (shfl_xor across the 16 row-lanes) -> 1 atomic per col.
// ---------------------------------------------------------------------------
#define ROWS 32
#define H_PITCH 520
#define HBYTES (ROWS * H_PITCH * 2)
#define WL_OFF (2 * HBYTES)
#define WL_HALF 16384
#define FUSED_LDS (WL_OFF + 65536 + 128)

template <int K1>
__global__ __launch_bounds__(512, 2) void fused3(
    const float* __restrict__ A0, const u16* __restrict__ W1t,
    const u16* __restrict__ W2t, const u16* __restrict__ W3t,
    const float* __restrict__ b1, const float* __restrict__ b2,
    const float* __restrict__ b3, const float* __restrict__ mask,
    float* __restrict__ out, int s2Off, int M) {
  extern __shared__ __align__(16) char ldsbuf[];
  u16* H1 = (u16*)ldsbuf;
  u16* H2 = (u16*)(ldsbuf + HBYTES);
  u16* Wl = (u16*)(ldsbuf + WL_OFF);

  const int tid  = threadIdx.x;
  const int wv   = tid >> 6;
  const int lane = tid & 63;
  const int m16  = lane & 15;
  const int quad = lane >> 4;
  const int row0 = blockIdx.x * ROWS;

  const int sr  = lane >> 2;
  const int skq = ((lane & 3) - (sr >> 1)) & 3;
  const int sw8 = (m16 * 4 + ((quad + (m16 >> 1)) & 3)) * 8;

  auto stage512 = [&](const u16* Wt, int K, int k0, int sel) {
    u16* base = Wl + sel * WL_HALF;
#pragma unroll
    for (int c = 0; c < 4; ++c) {
      int chunk = wv * 4 + c;
      gload_lds16(Wt + (size_t)(chunk * 16 + sr) * K + k0 + skq * 8,
                  base + chunk * 512);
    }
  };
  auto stage256 = [&](const u16* Wt, int K, int k0, int sel) {
    u16* base = Wl + sel * 8192;
#pragma unroll
    for (int c = 0; c < 2; ++c) {
      int chunk = wv * 2 + c;
      gload_lds16(Wt + (size_t)(chunk * 16 + sr) * K + k0 + skq * 8,
                  base + chunk * 512);
    }
  };

  int grow[2];
#pragma unroll
  for (int mi = 0; mi < 2; ++mi) {
    int r = row0 + mi * 16 + m16;
    grow[mi] = r < M ? r : (M - 1);
  }
  const float* ap[2];
#pragma unroll
  for (int mi = 0; mi < 2; ++mi) ap[mi] = A0 + (size_t)grow[mi] * K1 + quad * 8;

  {  // layer 1
    constexpr int NS1 = K1 / 32;
    stage512(W1t, K1, 0, 0);
    floatx4 acc[4][2];
#pragma unroll
    for (int i = 0; i < 4; i++)
#pragma unroll
      for (int j = 0; j < 2; j++) { floatx4 z = {0.f,0.f,0.f,0.f}; acc[i][j] = z; }
#pragma unroll
    for (int s = 0; s < NS1; ++s) {
      __syncthreads();
      if (s + 1 < NS1) stage512(W1t, K1, (s + 1) * 32, (s + 1) & 1);
      const u16* wb = Wl + (s & 1) * WL_HALF;
      short8 af[4], bx[2];
#pragma unroll
      for (int ni = 0; ni < 4; ++ni)
        af[ni] = *(const short8*)(wb + (wv * 4 + ni) * 512 + sw8);
#pragma unroll
      for (int mi = 0; mi < 2; ++mi)
        bx[mi] = pack8(*(const floatx4*)(ap[mi] + s * 32),
                       *(const floatx4*)(ap[mi] + s * 32 + 4));
#pragma unroll
      for (int ni = 0; ni < 4; ++ni)
#pragma unroll
        for (int mi = 0; mi < 2; ++mi)
          acc[ni][mi] = __builtin_amdgcn_mfma_f32_16x16x32_bf16(af[ni], bx[mi], acc[ni][mi], 0, 0, 0);
    }
    const int n0 = wv * 64;
#pragma unroll
    for (int ni = 0; ni < 4; ++ni) {
      const int nb = n0 + ni * 16 + quad * 4;
      floatx4 bb = *(const floatx4*)&b1[nb];
#pragma unroll
      for (int mi = 0; mi < 2; ++mi) {
        s4 h;
#pragma unroll
        for (int r = 0; r < 4; ++r) h[r] = bf16bits(lrelu(acc[ni][mi][r] + bb[r]));
        *(s4*)&H1[(mi * 16 + m16) * H_PITCH + nb] = h;
      }
    }
  }

  {  // layer 2
    stage512(W2t, 512, 0, 0);
    const u16* hp[2];
#pragma unroll
    for (int mi = 0; mi < 2; ++mi)
      hp[mi] = H1 + (mi * 16 + m16) * H_PITCH + quad * 8;
    floatx4 acc[4][2];
#pragma unroll
    for (int i = 0; i < 4; i++)
#pragma unroll
      for (int j = 0; j < 2; j++) { floatx4 z = {0.f,0.f,0.f,0.f}; acc[i][j] = z; }
    for (int s = 0; s < 16; ++s) {
      __syncthreads();
      if (s < 15) stage512(W2t, 512, (s + 1) * 32, (s + 1) & 1);
      const u16* wb = Wl + (s & 1) * WL_HALF;
      short8 af[4], bx[2];
#pragma unroll
      for (int ni = 0; ni < 4; ++ni)
        af[ni] = *(const short8*)(wb + (wv * 4 + ni) * 512 + sw8);
#pragma unroll
      for (int mi = 0; mi < 2; ++mi) bx[mi] = *(const short8*)(hp[mi] + s * 32);
#pragma unroll
      for (int ni = 0; ni < 4; ++ni)
#pragma unroll
        for (int mi = 0; mi < 2; ++mi)
          acc[ni][mi] = __builtin_amdgcn_mfma_f32_16x16x32_bf16(af[ni], bx[mi], acc[ni][mi], 0, 0, 0);
    }
    const int n0 = wv * 64;
#pragma unroll
    for (int ni = 0; ni < 4; ++ni) {
      const int nb = n0 + ni * 16 + quad * 4;
      floatx4 bb = *(const floatx4*)&b2[nb];
#pragma unroll
      for (int mi = 0; mi < 2; ++mi) {
        s4 h;
#pragma unroll
        for (int r = 0; r < 4; ++r) h[r] = bf16bits(lrelu(acc[ni][mi][r] + bb[r]));
        *(s4*)&H2[(mi * 16 + m16) * H_PITCH + nb] = h;
      }
    }
  }

  {  // layer 3 + fused s2 contribution
    stage256(W3t, 512, 0, 0);
    const u16* hp[2];
#pragma unroll
    for (int mi = 0; mi < 2; ++mi)
      hp[mi] = H2 + (mi * 16 + m16) * H_PITCH + quad * 8;
    floatx4 acc[2][2];
#pragma unroll
    for (int i = 0; i < 2; i++)
#pragma unroll
      for (int j = 0; j < 2; j++) { floatx4 z = {0.f,0.f,0.f,0.f}; acc[i][j] = z; }
    for (int s = 0; s < 16; ++s) {
      __syncthreads();
      if (s < 15) stage256(W3t, 512, (s + 1) * 32, (s + 1) & 1);
      const u16* wb = Wl + (s & 1) * 8192;
      short8 af[2], bx[2];
#pragma unroll
      for (int ni = 0; ni < 2; ++ni)
        af[ni] = *(const short8*)(wb + (wv * 2 + ni) * 512 + sw8);
#pragma unroll
      for (int mi = 0; mi < 2; ++mi) bx[mi] = *(const short8*)(hp[mi] + s * 32);
#pragma unroll
      for (int ni = 0; ni < 2; ++ni)
#pragma unroll
        for (int mi = 0; mi < 2; ++mi)
          acc[ni][mi] = __builtin_amdgcn_mfma_f32_16x16x32_bf16(af[ni], bx[mi], acc[ni][mi], 0, 0, 0);
    }
    const int n0 = wv * 32;
    float sv[2][4];
#pragma unroll
    for (int ni = 0; ni < 2; ++ni)
#pragma unroll
      for (int r = 0; r < 4; ++r) sv[ni][r] = 0.f;
#pragma unroll
    for (int mi = 0; mi < 2; ++mi) {
      const int r0 = row0 + mi * 16 + m16;
      if (r0 < M) {
        const float mk = mask[r0];
#pragma unroll
        for (int ni = 0; ni < 2; ++ni) {
          floatx4 bb = *(const floatx4*)&b3[n0 + ni * 16 + quad * 4];
#pragma unroll
          for (int r = 0; r < 4; ++r)
            sv[ni][r] += mk * lrelu(acc[ni][mi][r] + bb[r]);
        }
      }
    }
    // reduce over the 16 row-lanes (m16); xor keeps quad fixed
#pragma unroll
    for (int j = 1; j < 16; j <<= 1)
#pragma unroll
      for (int ni = 0; ni < 2; ++ni)
#pragma unroll
        for (int r = 0; r < 4; ++r)
          sv[ni][r] += __shfl_xor(sv[ni][r], j);
    if (m16 == 0) {
#pragma unroll
      for (int ni = 0; ni < 2; ++ni)
#pragma unroll
        for (int r = 0; r < 4; ++r)
          atomicAdd(out + s2Off + n0 + ni * 16 + quad * 4 + r, sv[ni][r]);
    }
  }
}

extern "C" void kernel_launch(void* const* d_in, const int* in_sizes, int n_in,
                              void* d_out, int out_size, void* d_ws, size_t ws_size,
                              hipStream_t stream) {
  (void)in_sizes; (void)n_in;
  constexpr int N_   = 100000;
  constexpr int MPAD = 100096;               // 782 * 128
  constexpr int HM   = MPAD / 2;             // 50048 = 391 * 128
  constexpr int IND  = 128;
  constexpr int H1D  = 512;
  constexpr int H2D  = 512;
  constexpr int OUTD = 256;
  constexpr int NDAG = 2000;

  const float* X    = (const float*)d_in[0];
  const int*   dag  = (const int*)d_in[1];
  const float* mask = (const float*)d_in[2];
  const float* W1 = (const float*)d_in[3];
  const float* b1 = (const float*)d_in[4];
  const float* W2 = (const float*)d_in[5];
  const float* b2 = (const float*)d_in[6];
  const float* W3 = (const float*)d_in[7];
  const float* b3 = (const float*)d_in[8];
  const float* W4 = (const float*)d_in[9];
  const float* b4 = (const float*)d_in[10];
  const float* W5 = (const float*)d_in[11];
  const float* b5 = (const float*)d_in[12];
  const float* W6 = (const float*)d_in[13];
  const float* b6 = (const float*)d_in[14];

  // fixed buffers ~30 MB; Y1/Y2 sized by available workspace
  const size_t fixedBytes = 29ull * 1024 * 1024;
  const bool singlePass =
      ws_size >= fixedBytes + 2ull * (size_t)MPAD * H1D * 2 + (1u << 20);
  const int YR = singlePass ? MPAD : HM;   // rows per Y buffer

  char* ws = (char*)d_ws;
  auto alloc = [&](size_t bytes) {
    char* p = ws;
    ws += (bytes + 255) & ~(size_t)255;
    return p;
  };
  u16* W1t = (u16*)alloc((size_t)H1D * IND * 2);
  u16* W2t = (u16*)alloc((size_t)H2D * H1D * 2);
  u16* W3t = (u16*)alloc((size_t)OUTD * H2D * 2);
  u16* W4t = (u16*)alloc((size_t)H1D * OUTD * 2);
  u16* W5t = (u16*)alloc((size_t)H2D * H1D * 2);
  u16* W6t = (u16*)alloc((size_t)OUTD * H2D * 2);
  int* hist   = (int*)alloc((size_t)NDAG * 4);
  int* cursor = (int*)alloc((size_t)NDAG * 4);
  int* perm   = (int*)alloc((size_t)N_ * 4);
  int* dsort  = (int*)alloc((size_t)MPAD * 4);
  u16* Xb = (u16*)alloc((size_t)MPAD * IND * 2);
  u16* Y1 = (u16*)alloc((size_t)YR * H1D * 2);
  u16* Y2 = (u16*)alloc((size_t)YR * H2D * 2);

  float* out = (float*)d_out;
  float* s1  = out;                // [2000][256] f32, output 0
  const int s2Off = NDAG * OUTD;

  constexpr int LDS_GEMM = 32768;
  constexpr int LDS_SEG  = 34816;  // 4 waves x 64x68 bf16 scratch (overlaps staging)
  hipFuncSetAttribute(reinterpret_cast<const void*>(&layer_gemm<128, 512, 0>),
                      hipFuncAttributeMaxDynamicSharedMemorySize, LDS_GEMM);
  hipFuncSetAttribute(reinterpret_cast<const void*>(&layer_gemm<512, 512, 0>),
                      hipFuncAttributeMaxDynamicSharedMemorySize, LDS_GEMM);
  hipFuncSetAttribute(reinterpret_cast<const void*>(&layer_gemm<512, 256, 1>),
                      hipFuncAttributeMaxDynamicSharedMemorySize, LDS_SEG);
  hipFuncSetAttribute(reinterpret_cast<const void*>(&fused3<OUTD>),
                      hipFuncAttributeMaxDynamicSharedMemorySize, FUSED_LDS);

  hipMemsetAsync(out, 0, (size_t)out_size * 4, stream);
  hipMemsetAsync(hist, 0, (size_t)NDAG * 4, stream);
  hipMemsetAsync(dsort + N_, 0xFF, (size_t)(MPAD - N_) * 4, stream);   // -1 tail
  hipMemsetAsync(Xb + (size_t)N_ * IND, 0, (size_t)(MPAD - N_) * IND * 2, stream);

  // counting sort by dag id
  hist_kernel<<<(N_ + 255) / 256, 256, 0, stream>>>(dag, hist, N_);
  scan_offsets<<<1, 256, 0, stream>>>(hist, cursor);
  scatter_kernel<<<(N_ + 255) / 256, 256, 0, stream>>>(dag, cursor, perm, dsort, N_);

  // weight transposes + X gather/convert
  transpose_all<<<dim3(16, 16, 6), 256, 0, stream>>>(W1, W2, W3, W4, W5, W6,
                                                     W1t, W2t, W3t, W4t, W5t, W6t);
  xb_conv<<<(N_ * 32 + 255) / 256, 256, 0, stream>>>(X, perm, Xb, N_);

  // node stack (col-group = fast grid dim for A-tile L3 reuse)
  const int passes = singlePass ? 1 : 2;
  const int MR = singlePass ? MPAD : HM;
  for (int h = 0; h < passes; ++h) {
    const size_t ro = (size_t)h * HM;
    layer_gemm<128, 512, 0><<<dim3(4, MR / 128), 256, LDS_GEMM, stream>>>(
        Xb + ro * IND, W1t, b1, Y1, nullptr, nullptr);
    layer_gemm<512, 512, 0><<<dim3(4, MR / 128), 256, LDS_GEMM, stream>>>(
        Y1, W2t, b2, Y2, nullptr, nullptr);
    layer_gemm<512, 256, 1><<<dim3(2, MR / 128), 256, LDS_SEG, stream>>>(
        Y2, W3t, b3, nullptr, s1, dsort + ro);
  }

  // global stack on s1 (f32 in d_out); s2 fused via atomics into out[s2Off..]
  fused3<OUTD><<<(NDAG + ROWS - 1) / ROWS, 512, FUSED_LDS, stream>>>(
      s1, W4t, W5t, W6t, b4, b5, b6, mask, out, s2Off, NDAG);
}